// Round 4
// baseline (1020.094 us; speedup 1.0000x reference)
//
#include <hip/hip_runtime.h>

#define NTOK 49
#define CC   128
#define NHEADS 4
#define HWW  56
#define HW2  3136
#define SCALE_F 0.17677669529663687f

typedef __attribute__((ext_vector_type(8))) short s16x8;
typedef __attribute__((ext_vector_type(4))) float f32x4;

static __device__ __forceinline__ unsigned short f2bf(float f) {
  unsigned int u = __float_as_uint(f);
  u += 0x7fffu + ((u >> 16) & 1u);
  return (unsigned short)(u >> 16);
}
// 32-col-local swizzle (keeps head column ranges disjoint), 16B-group aligned
static __device__ __forceinline__ int swz4(int row, int col) { return col ^ ((row & 3) << 3); }
// 64-col-local swizzle for PB
static __device__ __forceinline__ int swz8(int row, int col) { return col ^ ((row & 7) << 3); }

__global__ void wconv_kernel(const float* __restrict__ Wq, const float* __restrict__ Wk,
                             const float* __restrict__ Wv, const float* __restrict__ Wo,
                             unsigned short* __restrict__ dst) {
  int i = blockIdx.x * 256 + threadIdx.x;
  const float* src = (i < 16384) ? Wq : (i < 32768) ? Wk : (i < 49152) ? Wv : Wo;
  float v = src[i & 16383];
  if (i < 16384) v *= SCALE_F;          // fold attention scale into Wq
  dst[i] = f2bf(v);
}

__global__ __launch_bounds__(256, 3)
void winattn_kernel(const float* __restrict__ Xq, const float* __restrict__ Xk,
                    const float* __restrict__ Xv,
                    const unsigned short* __restrict__ Wbf,
                    const float* __restrict__ bq, const float* __restrict__ bk,
                    const float* __restrict__ bv, const float* __restrict__ bo,
                    const float* __restrict__ rpb,
                    float* __restrict__ out_x,
                    float* __restrict__ out_ctx)
{
  // 51968 B total -> 3 blocks/CU
  __shared__ alignas(16) unsigned short smem[25984];
  unsigned short* Buf0 = smem;            // [49][128] raw q -> Q (in-place) -> attn-out (per-head cols)
  unsigned short* Buf1 = smem + 6272;     // [49][128] raw k -> K (in-place)
  unsigned short* VT   = smem + 12544;    // [128][56]: (h*32+d) x token, V^T
  unsigned short* Buf2 = smem + 19712;    // [49][128] raw v -> PB ping-pong (2 x [49][64])
  unsigned short* PB0  = Buf2;
  unsigned short* PB1  = Buf2 + 3136;

  const int tid = threadIdx.x;
  const int wv  = tid >> 6;
  const int l   = tid & 63;
  const int lr  = l & 15;   // MFMA lane row/col
  const int lg  = l >> 4;   // MFMA k-group

  // XCD-bijective swizzle (4096 % 8 == 0): same-band windows share an XCD L2
  const int win  = (blockIdx.x & 7) * 512 + (blockIdx.x >> 3);
  const int bimg = win >> 6;
  const int r0   = ((win >> 3) & 7) * 7;
  const int c0   = (win & 7) * 7;

  // ---- Phase 0: zero VT (padding tokens must be finite/zero) + stage q,k,v
  {
    unsigned int* vz = (unsigned int*)VT;
    #pragma unroll
    for (int i = 0; i < 14; ++i) vz[tid + i*256] = 0u;   // 3584 dwords = 14336 B
    #pragma unroll
    for (int k = 0; k < 4; ++k) {
      int t = tid + k*256;
      if (t < 896) {                       // task = (channel ci, window-row si)
        int ci = t / 7, si = t - (t/7)*7;
        size_t off = (size_t)bimg*CC*HW2 + (size_t)ci*HW2 + (size_t)(r0+si)*HWW + c0;
        int tokb = si*7;
        #pragma unroll
        for (int sj = 0; sj < 7; ++sj) {
          int tok = tokb + sj;
          int di = tok*CC + swz4(tok, ci);
          Buf0[di] = f2bf(Xq[off+sj]);
          Buf1[di] = f2bf(Xk[off+sj]);
          Buf2[di] = f2bf(Xv[off+sj]);
        }
      }
    }
  }
  __syncthreads();

  // proj read-half: acc[mt][ntl] = src * W^T (bias folded at write)
  auto projR = [&](const unsigned short* __restrict__ src, const unsigned short* __restrict__ Wg,
                   const float* __restrict__ bias, float bscale,
                   f32x4 (&acc)[4][2], float (&bb)[2]) {
    s16x8 bfr[2][4];
    #pragma unroll
    for (int ntl = 0; ntl < 2; ++ntl) {
      int col = wv*32 + ntl*16 + lr;
      bb[ntl] = bias[col] * bscale;
      #pragma unroll
      for (int ks = 0; ks < 4; ++ks)
        bfr[ntl][ks] = *(const s16x8*)(Wg + col*CC + ks*32 + lg*8);
    }
    #pragma unroll
    for (int mt = 0; mt < 4; ++mt) {
      int ar = mt*16 + lr;
      s16x8 af[4];
      #pragma unroll
      for (int ks = 0; ks < 4; ++ks)
        af[ks] = *(const s16x8*)(src + ar*CC + swz4(ar, ks*32 + lg*8));
      #pragma unroll
      for (int ntl = 0; ntl < 2; ++ntl) {
        f32x4 a = {0.f,0.f,0.f,0.f};
        #pragma unroll
        for (int ks = 0; ks < 4; ++ks)
          a = __builtin_amdgcn_mfma_f32_16x16x32_bf16(af[ks], bfr[ntl][ks], a, 0,0,0);
        acc[mt][ntl] = a;
      }
    }
  };
  auto projW = [&](unsigned short* __restrict__ dst, f32x4 (&acc)[4][2], float (&bb)[2]) {
    #pragma unroll
    for (int mt = 0; mt < 4; ++mt) {
      #pragma unroll
      for (int ntl = 0; ntl < 2; ++ntl) {
        int col = wv*32 + ntl*16 + lr;
        #pragma unroll
        for (int r = 0; r < 4; ++r) {
          int row = mt*16 + lg*4 + r;     // C/D: row=(l>>4)*4+r, col=l&15
          if (row < NTOK)
            dst[row*CC + swz4(row, col)] = f2bf(acc[mt][ntl][r] + bb[ntl]);
        }
      }
    }
  };

  f32x4 acc[4][2]; float bb[2];
  projR(Buf0, Wbf, bq, SCALE_F, acc, bb);          // Q (scaled)
  __syncthreads();
  projW(Buf0, acc, bb);                            // Buf0 = Q
  projR(Buf1, Wbf + 16384, bk, 1.f, acc, bb);      // K
  __syncthreads();
  projW(Buf1, acc, bb);                            // Buf1 = K
  { // V projection: Buf2 -> VT (distinct region, no hoist needed)
    s16x8 bfr[2][4]; float vb[2];
    #pragma unroll
    for (int ntl = 0; ntl < 2; ++ntl) {
      int col = wv*32 + ntl*16 + lr;
      vb[ntl] = bv[col];
      #pragma unroll
      for (int ks = 0; ks < 4; ++ks)
        bfr[ntl][ks] = *(const s16x8*)(Wbf + 32768 + col*CC + ks*32 + lg*8);
    }
    #pragma unroll
    for (int mt = 0; mt < 4; ++mt) {
      int ar = mt*16 + lr;
      s16x8 af[4];
      #pragma unroll
      for (int ks = 0; ks < 4; ++ks)
        af[ks] = *(const s16x8*)(Buf2 + ar*CC + swz4(ar, ks*32 + lg*8));
      #pragma unroll
      for (int ntl = 0; ntl < 2; ++ntl) {
        f32x4 a = {0.f,0.f,0.f,0.f};
        #pragma unroll
        for (int ks = 0; ks < 4; ++ks)
          a = __builtin_amdgcn_mfma_f32_16x16x32_bf16(af[ks], bfr[ntl][ks], a, 0,0,0);
        int col = wv*32 + ntl*16 + lr;
        #pragma unroll
        for (int r = 0; r < 4; ++r) {
          int row = mt*16 + lg*4 + r;   // token
          if (row < NTOK) VT[col*56 + row] = f2bf(a[r] + vb[ntl]);
        }
      }
    }
  }
  __syncthreads();

  // qkt + in-register softmax + ctx store + PB write, one head
  auto attnh = [&](int h, unsigned short* __restrict__ PBw, float (&rinv)[4]) {
    int arow = wv*16 + lr;
    s16x8 aq = *(const s16x8*)(Buf0 + arow*CC + swz4(arow, h*32 + lg*8));
    f32x4 sa[4];
    #pragma unroll
    for (int nt = 0; nt < 4; ++nt) {
      int brow = nt*16 + lr;
      s16x8 kb = *(const s16x8*)(Buf1 + brow*CC + swz4(brow, h*32 + lg*8));
      f32x4 z = {0.f,0.f,0.f,0.f};
      sa[nt] = __builtin_amdgcn_mfma_f32_16x16x32_bf16(aq, kb, z, 0,0,0);
    }
    float vals[4][4];                     // [r][nt]
    #pragma unroll
    for (int r = 0; r < 4; ++r) {
      int row = wv*16 + lg*4 + r;
      int i1 = row / 7, j1 = row - (row/7)*7;
      #pragma unroll
      for (int nt = 0; nt < 4; ++nt) {
        int col = nt*16 + lr;
        float s = -1e30f;
        if (row < NTOK && col < NTOK) {
          int i2 = col / 7, j2 = col - (col/7)*7;
          s = sa[nt][r] + rpb[((i1-i2+6)*13 + (j1-j2+6))*NHEADS + h];
        }
        vals[r][nt] = s;
      }
    }
    size_t cbase = ((size_t)win*NHEADS + h)*(NTOK*NTOK);
    #pragma unroll
    for (int r = 0; r < 4; ++r) {
      int row = wv*16 + lg*4 + r;
      float mx = fmaxf(fmaxf(vals[r][0], vals[r][1]), fmaxf(vals[r][2], vals[r][3]));
      mx = fmaxf(mx, __shfl_xor(mx, 1, 16));
      mx = fmaxf(mx, __shfl_xor(mx, 2, 16));
      mx = fmaxf(mx, __shfl_xor(mx, 4, 16));
      mx = fmaxf(mx, __shfl_xor(mx, 8, 16));
      float e0 = __expf(vals[r][0]-mx), e1 = __expf(vals[r][1]-mx);
      float e2 = __expf(vals[r][2]-mx), e3 = __expf(vals[r][3]-mx);
      float sum = (e0+e1)+(e2+e3);
      sum += __shfl_xor(sum, 1, 16);
      sum += __shfl_xor(sum, 2, 16);
      sum += __shfl_xor(sum, 4, 16);
      sum += __shfl_xor(sum, 8, 16);
      float ri = 1.f / sum;
      rinv[r] = ri;
      if (row < NTOK) {
        float e[4] = {e0, e1, e2, e3};
        #pragma unroll
        for (int nt = 0; nt < 4; ++nt) {
          int col = nt*16 + lr;
          PBw[row*64 + swz8(row, col)] = f2bf(e[nt]);       // cols>=49 store exp(-huge)=0
          if (col < NTOK)
            __builtin_nontemporal_store(e[nt]*ri, out_ctx + cbase + row*NTOK + col);
        }
      }
    }
  };

  // out_h = P*V_h, normalized by rinv (same lane<->row mapping as softmax)
  auto pv = [&](int h, const unsigned short* __restrict__ PBr, const float (&rinv)[4]) {
    int arow = wv*16 + lr; if (arow > 48) arow = 48;   // clamp: stay inside smem
    s16x8 pa[2];
    #pragma unroll
    for (int ks = 0; ks < 2; ++ks)
      pa[ks] = *(const s16x8*)(PBr + arow*64 + swz8(arow, ks*32 + lg*8));
    #pragma unroll
    for (int nt = 0; nt < 2; ++nt) {
      int dd = nt*16 + lr;
      f32x4 a = {0.f,0.f,0.f,0.f};
      #pragma unroll
      for (int ks = 0; ks < 2; ++ks) {
        s16x8 vb8 = *(const s16x8*)(VT + (h*32+dd)*56 + ks*32 + lg*8);
        a = __builtin_amdgcn_mfma_f32_16x16x32_bf16(pa[ks], vb8, a, 0,0,0);
      }
      #pragma unroll
      for (int r = 0; r < 4; ++r) {
        int row = wv*16 + lg*4 + r;
        if (row < NTOK) {
          int col = h*32 + nt*16 + lr;
          Buf0[row*CC + swz4(row, col)] = f2bf(a[r] * rinv[r]);  // dead Q cols
        }
      }
    }
  };

  float rinvA[4], rinvB[4];
  attnh(0, PB0, rinvA);
  __syncthreads();
  pv(0, PB0, rinvA); attnh(1, PB1, rinvB);
  __syncthreads();
  pv(1, PB1, rinvB); attnh(2, PB0, rinvA);
  __syncthreads();
  pv(2, PB0, rinvA); attnh(3, PB1, rinvB);
  __syncthreads();
  pv(3, PB1, rinvB);
  __syncthreads();

  { // output projection: x = attn_out @ Wo^T + bo -> [B,C,H,W] fp32
    const unsigned short* Wg = Wbf + 49152;
    s16x8 bfr[2][4]; float ob[2];
    #pragma unroll
    for (int ntl = 0; ntl < 2; ++ntl) {
      int col = wv*32 + ntl*16 + lr;
      ob[ntl] = bo[col];
      #pragma unroll
      for (int ks = 0; ks < 4; ++ks)
        bfr[ntl][ks] = *(const s16x8*)(Wg + col*CC + ks*32 + lg*8);
    }
    #pragma unroll
    for (int mt = 0; mt < 4; ++mt) {
      int ar = mt*16 + lr;
      s16x8 af[4];
      #pragma unroll
      for (int ks = 0; ks < 4; ++ks)
        af[ks] = *(const s16x8*)(Buf0 + ar*CC + swz4(ar, ks*32 + lg*8));
      #pragma unroll
      for (int ntl = 0; ntl < 2; ++ntl) {
        f32x4 a = {0.f,0.f,0.f,0.f};
        #pragma unroll
        for (int ks = 0; ks < 4; ++ks)
          a = __builtin_amdgcn_mfma_f32_16x16x32_bf16(af[ks], bfr[ntl][ks], a, 0,0,0);
        int col = wv*32 + ntl*16 + lr;
        #pragma unroll
        for (int r = 0; r < 4; ++r) {
          int row = mt*16 + lg*4 + r;
          if (row < NTOK) {
            int ii = row / 7, jj = row - (row/7)*7;
            size_t off = ((size_t)(bimg*CC + col))*HW2 + (size_t)(r0+ii)*HWW + (c0+jj);
            __builtin_nontemporal_store(a[r] + ob[ntl], out_x + off);
          }
        }
      }
    }
  }
}

extern "C" void kernel_launch(void* const* d_in, const int* in_sizes, int n_in,
                              void* d_out, int out_size, void* d_ws, size_t ws_size,
                              hipStream_t stream) {
  (void)in_sizes; (void)n_in; (void)out_size; (void)ws_size;
  const float* query = (const float*)d_in[0];
  const float* key   = (const float*)d_in[1];
  const float* value = (const float*)d_in[2];
  const float* Wq = (const float*)d_in[3];
  const float* bq = (const float*)d_in[4];
  const float* Wk = (const float*)d_in[5];
  const float* bk = (const float*)d_in[6];
  const float* Wv = (const float*)d_in[7];
  const float* bv = (const float*)d_in[8];
  const float* Wo = (const float*)d_in[9];
  const float* bo = (const float*)d_in[10];
  const float* rpb = (const float*)d_in[11];

  unsigned short* Wbf = (unsigned short*)d_ws;           // 4 x [128][128] bf16
  float* out_x   = (float*)d_out;                        // [64][128][56][56] fp32
  float* out_ctx = out_x + (size_t)64*CC*HW2;            // [4096][4][49][49] fp32

  wconv_kernel<<<256, 256, 0, stream>>>(Wq, Wk, Wv, Wo, Wbf);
  winattn_kernel<<<4096, 256, 0, stream>>>(query, key, value, Wbf, bq, bk, bv, bo, rpb,
                                           out_x, out_ctx);
}

// Round 5
// 350.239 us; speedup vs baseline: 2.9126x; 2.9126x over previous
//
#include <hip/hip_runtime.h>

#define NTOK 49
#define CC   128
#define NHEADS 4
#define HWW  56
#define HW2  3136
#define SCALE_F 0.17677669529663687f

typedef __attribute__((ext_vector_type(8))) short s16x8;
typedef __attribute__((ext_vector_type(4))) float f32x4;

static __device__ __forceinline__ unsigned short f2bf(float f) {
  unsigned int u = __float_as_uint(f);
  u += 0x7fffu + ((u >> 16) & 1u);
  return (unsigned short)(u >> 16);
}
// 32-col-local swizzle (keeps head column ranges disjoint), 16B-group aligned
static __device__ __forceinline__ int swz4(int row, int col) { return col ^ ((row & 3) << 3); }
// 64-col-local swizzle for PB
static __device__ __forceinline__ int swz8(int row, int col) { return col ^ ((row & 7) << 3); }

__global__ void wconv_kernel(const float* __restrict__ Wq, const float* __restrict__ Wk,
                             const float* __restrict__ Wv, const float* __restrict__ Wo,
                             unsigned short* __restrict__ dst) {
  int i = blockIdx.x * 256 + threadIdx.x;
  const float* src = (i < 16384) ? Wq : (i < 32768) ? Wk : (i < 49152) ? Wv : Wo;
  float v = src[i & 16383];
  if (i < 16384) v *= SCALE_F;          // fold attention scale into Wq
  dst[i] = f2bf(v);
}

__global__ __launch_bounds__(256, 3)
void winattn_kernel(const float* __restrict__ Xq, const float* __restrict__ Xk,
                    const float* __restrict__ Xv,
                    const unsigned short* __restrict__ Wbf,
                    const float* __restrict__ bq, const float* __restrict__ bk,
                    const float* __restrict__ bv, const float* __restrict__ bo,
                    const float* __restrict__ rpb,
                    float* __restrict__ out_x,
                    float* __restrict__ out_ctx)
{
  // 51968 B total -> 3 blocks/CU
  __shared__ alignas(16) unsigned short smem[25984];
  unsigned short* Buf0 = smem;            // [49][128] raw q -> Q (in-place) -> attn-out (per-head cols)
  unsigned short* Buf1 = smem + 6272;     // [49][128] raw k -> K (in-place)
  unsigned short* VT   = smem + 12544;    // [128][56]: (h*32+d) x token, V^T
  unsigned short* Buf2 = smem + 19712;    // [49][128] raw v -> PB ping-pong (2 x [49][64])
  unsigned short* PB0  = Buf2;
  unsigned short* PB1  = Buf2 + 3136;

  const int tid = threadIdx.x;
  const int wv  = tid >> 6;
  const int l   = tid & 63;
  const int lr  = l & 15;   // MFMA lane row/col
  const int lg  = l >> 4;   // MFMA k-group

  // XCD-bijective swizzle (4096 % 8 == 0): same-band windows share an XCD L2
  const int win  = (blockIdx.x & 7) * 512 + (blockIdx.x >> 3);
  const int bimg = win >> 6;
  const int r0   = ((win >> 3) & 7) * 7;
  const int c0   = (win & 7) * 7;

  // ---- Phase 0: zero VT (padding tokens must be finite/zero) + stage q,k,v
  {
    unsigned int* vz = (unsigned int*)VT;
    #pragma unroll
    for (int i = 0; i < 14; ++i) vz[tid + i*256] = 0u;   // 3584 dwords = 14336 B
    #pragma unroll
    for (int k = 0; k < 4; ++k) {
      int t = tid + k*256;
      if (t < 896) {                       // task = (channel ci, window-row si)
        int ci = t / 7, si = t - (t/7)*7;
        size_t off = (size_t)bimg*CC*HW2 + (size_t)ci*HW2 + (size_t)(r0+si)*HWW + c0;
        int tokb = si*7;
        #pragma unroll
        for (int sj = 0; sj < 7; ++sj) {
          int tok = tokb + sj;
          int di = tok*CC + swz4(tok, ci);
          Buf0[di] = f2bf(Xq[off+sj]);
          Buf1[di] = f2bf(Xk[off+sj]);
          Buf2[di] = f2bf(Xv[off+sj]);
        }
      }
    }
  }
  __syncthreads();

  // proj read-half: acc[mt][ntl] = src * W^T (bias folded at write)
  auto projR = [&](const unsigned short* __restrict__ src, const unsigned short* __restrict__ Wg,
                   const float* __restrict__ bias, float bscale,
                   f32x4 (&acc)[4][2], float (&bb)[2]) {
    s16x8 bfr[2][4];
    #pragma unroll
    for (int ntl = 0; ntl < 2; ++ntl) {
      int col = wv*32 + ntl*16 + lr;
      bb[ntl] = bias[col] * bscale;
      #pragma unroll
      for (int ks = 0; ks < 4; ++ks)
        bfr[ntl][ks] = *(const s16x8*)(Wg + col*CC + ks*32 + lg*8);
    }
    #pragma unroll
    for (int mt = 0; mt < 4; ++mt) {
      int ar = mt*16 + lr;
      s16x8 af[4];
      #pragma unroll
      for (int ks = 0; ks < 4; ++ks)
        af[ks] = *(const s16x8*)(src + ar*CC + swz4(ar, ks*32 + lg*8));
      #pragma unroll
      for (int ntl = 0; ntl < 2; ++ntl) {
        f32x4 a = {0.f,0.f,0.f,0.f};
        #pragma unroll
        for (int ks = 0; ks < 4; ++ks)
          a = __builtin_amdgcn_mfma_f32_16x16x32_bf16(af[ks], bfr[ntl][ks], a, 0,0,0);
        acc[mt][ntl] = a;
      }
    }
  };
  auto projW = [&](unsigned short* __restrict__ dst, f32x4 (&acc)[4][2], float (&bb)[2]) {
    #pragma unroll
    for (int mt = 0; mt < 4; ++mt) {
      #pragma unroll
      for (int ntl = 0; ntl < 2; ++ntl) {
        int col = wv*32 + ntl*16 + lr;
        #pragma unroll
        for (int r = 0; r < 4; ++r) {
          int row = mt*16 + lg*4 + r;     // C/D: row=(l>>4)*4+r, col=l&15
          if (row < NTOK)
            dst[row*CC + swz4(row, col)] = f2bf(acc[mt][ntl][r] + bb[ntl]);
        }
      }
    }
  };

  f32x4 acc[4][2]; float bb[2];
  projR(Buf0, Wbf, bq, SCALE_F, acc, bb);          // Q (scaled)
  __syncthreads();
  projW(Buf0, acc, bb);                            // Buf0 = Q
  projR(Buf1, Wbf + 16384, bk, 1.f, acc, bb);      // K
  __syncthreads();
  projW(Buf1, acc, bb);                            // Buf1 = K
  { // V projection: Buf2 -> VT (distinct region, no hoist needed)
    s16x8 bfr[2][4]; float vb[2];
    #pragma unroll
    for (int ntl = 0; ntl < 2; ++ntl) {
      int col = wv*32 + ntl*16 + lr;
      vb[ntl] = bv[col];
      #pragma unroll
      for (int ks = 0; ks < 4; ++ks)
        bfr[ntl][ks] = *(const s16x8*)(Wbf + 32768 + col*CC + ks*32 + lg*8);
    }
    #pragma unroll
    for (int mt = 0; mt < 4; ++mt) {
      int ar = mt*16 + lr;
      s16x8 af[4];
      #pragma unroll
      for (int ks = 0; ks < 4; ++ks)
        af[ks] = *(const s16x8*)(Buf2 + ar*CC + swz4(ar, ks*32 + lg*8));
      #pragma unroll
      for (int ntl = 0; ntl < 2; ++ntl) {
        f32x4 a = {0.f,0.f,0.f,0.f};
        #pragma unroll
        for (int ks = 0; ks < 4; ++ks)
          a = __builtin_amdgcn_mfma_f32_16x16x32_bf16(af[ks], bfr[ntl][ks], a, 0,0,0);
        int col = wv*32 + ntl*16 + lr;
        #pragma unroll
        for (int r = 0; r < 4; ++r) {
          int row = mt*16 + lg*4 + r;   // token
          if (row < NTOK) VT[col*56 + row] = f2bf(a[r] + vb[ntl]);
        }
      }
    }
  }
  __syncthreads();

  // qkt + in-register softmax + ctx store + PB write, one head
  auto attnh = [&](int h, unsigned short* __restrict__ PBw, float (&rinv)[4]) {
    int arow = wv*16 + lr;
    s16x8 aq = *(const s16x8*)(Buf0 + arow*CC + swz4(arow, h*32 + lg*8));
    f32x4 sa[4];
    #pragma unroll
    for (int nt = 0; nt < 4; ++nt) {
      int brow = nt*16 + lr;
      s16x8 kb = *(const s16x8*)(Buf1 + brow*CC + swz4(brow, h*32 + lg*8));
      f32x4 z = {0.f,0.f,0.f,0.f};
      sa[nt] = __builtin_amdgcn_mfma_f32_16x16x32_bf16(aq, kb, z, 0,0,0);
    }
    float vals[4][4];                     // [r][nt]
    #pragma unroll
    for (int r = 0; r < 4; ++r) {
      int row = wv*16 + lg*4 + r;
      int i1 = row / 7, j1 = row - (row/7)*7;
      #pragma unroll
      for (int nt = 0; nt < 4; ++nt) {
        int col = nt*16 + lr;
        float s = -1e30f;
        if (row < NTOK && col < NTOK) {
          int i2 = col / 7, j2 = col - (col/7)*7;
          s = sa[nt][r] + rpb[((i1-i2+6)*13 + (j1-j2+6))*NHEADS + h];
        }
        vals[r][nt] = s;
      }
    }
    size_t cbase = ((size_t)win*NHEADS + h)*(NTOK*NTOK);
    #pragma unroll
    for (int r = 0; r < 4; ++r) {
      int row = wv*16 + lg*4 + r;
      float mx = fmaxf(fmaxf(vals[r][0], vals[r][1]), fmaxf(vals[r][2], vals[r][3]));
      mx = fmaxf(mx, __shfl_xor(mx, 1, 16));
      mx = fmaxf(mx, __shfl_xor(mx, 2, 16));
      mx = fmaxf(mx, __shfl_xor(mx, 4, 16));
      mx = fmaxf(mx, __shfl_xor(mx, 8, 16));
      float e0 = __expf(vals[r][0]-mx), e1 = __expf(vals[r][1]-mx);
      float e2 = __expf(vals[r][2]-mx), e3 = __expf(vals[r][3]-mx);
      float sum = (e0+e1)+(e2+e3);
      sum += __shfl_xor(sum, 1, 16);
      sum += __shfl_xor(sum, 2, 16);
      sum += __shfl_xor(sum, 4, 16);
      sum += __shfl_xor(sum, 8, 16);
      float ri = 1.f / sum;
      rinv[r] = ri;
      if (row < NTOK) {
        float e[4] = {e0, e1, e2, e3};
        #pragma unroll
        for (int nt = 0; nt < 4; ++nt) {
          int col = nt*16 + lr;
          PBw[row*64 + swz8(row, col)] = f2bf(e[nt]);       // cols>=49 store exp(-huge)=0
          if (col < NTOK)
            out_ctx[cbase + row*NTOK + col] = e[nt]*ri;     // plain store: L2 merges partial lines
        }
      }
    }
  };

  // out_h = P*V_h, normalized by rinv (same lane<->row mapping as softmax)
  auto pv = [&](int h, const unsigned short* __restrict__ PBr, const float (&rinv)[4]) {
    int arow = wv*16 + lr; if (arow > 48) arow = 48;   // clamp: stay inside smem
    s16x8 pa[2];
    #pragma unroll
    for (int ks = 0; ks < 2; ++ks)
      pa[ks] = *(const s16x8*)(PBr + arow*64 + swz8(arow, ks*32 + lg*8));
    #pragma unroll
    for (int nt = 0; nt < 2; ++nt) {
      int dd = nt*16 + lr;
      f32x4 a = {0.f,0.f,0.f,0.f};
      #pragma unroll
      for (int ks = 0; ks < 2; ++ks) {
        s16x8 vb8 = *(const s16x8*)(VT + (h*32+dd)*56 + ks*32 + lg*8);
        a = __builtin_amdgcn_mfma_f32_16x16x32_bf16(pa[ks], vb8, a, 0,0,0);
      }
      #pragma unroll
      for (int r = 0; r < 4; ++r) {
        int row = wv*16 + lg*4 + r;
        if (row < NTOK) {
          int col = h*32 + nt*16 + lr;
          Buf0[row*CC + swz4(row, col)] = f2bf(a[r] * rinv[r]);  // dead Q cols
        }
      }
    }
  };

  float rinvA[4], rinvB[4];
  attnh(0, PB0, rinvA);
  __syncthreads();
  pv(0, PB0, rinvA); attnh(1, PB1, rinvB);
  __syncthreads();
  pv(1, PB1, rinvB); attnh(2, PB0, rinvA);
  __syncthreads();
  pv(2, PB0, rinvA); attnh(3, PB1, rinvB);
  __syncthreads();
  pv(3, PB1, rinvB);
  __syncthreads();

  { // output projection: x = attn_out @ Wo^T + bo -> [B,C,H,W] fp32
    const unsigned short* Wg = Wbf + 49152;
    s16x8 bfr[2][4]; float ob[2];
    #pragma unroll
    for (int ntl = 0; ntl < 2; ++ntl) {
      int col = wv*32 + ntl*16 + lr;
      ob[ntl] = bo[col];
      #pragma unroll
      for (int ks = 0; ks < 4; ++ks)
        bfr[ntl][ks] = *(const s16x8*)(Wg + col*CC + ks*32 + lg*8);
    }
    #pragma unroll
    for (int mt = 0; mt < 4; ++mt) {
      int ar = mt*16 + lr;
      s16x8 af[4];
      #pragma unroll
      for (int ks = 0; ks < 4; ++ks)
        af[ks] = *(const s16x8*)(Buf0 + ar*CC + swz4(ar, ks*32 + lg*8));
      #pragma unroll
      for (int ntl = 0; ntl < 2; ++ntl) {
        f32x4 a = {0.f,0.f,0.f,0.f};
        #pragma unroll
        for (int ks = 0; ks < 4; ++ks)
          a = __builtin_amdgcn_mfma_f32_16x16x32_bf16(af[ks], bfr[ntl][ks], a, 0,0,0);
        int col = wv*32 + ntl*16 + lr;
        #pragma unroll
        for (int r = 0; r < 4; ++r) {
          int row = mt*16 + lg*4 + r;
          if (row < NTOK) {
            int ii = row / 7, jj = row - (row/7)*7;
            size_t off = ((size_t)(bimg*CC + col))*HW2 + (size_t)(r0+ii)*HWW + (c0+jj);
            out_x[off] = a[r] + ob[ntl];             // plain store: L2 merges partial lines
          }
        }
      }
    }
  }
}

extern "C" void kernel_launch(void* const* d_in, const int* in_sizes, int n_in,
                              void* d_out, int out_size, void* d_ws, size_t ws_size,
                              hipStream_t stream) {
  (void)in_sizes; (void)n_in; (void)out_size; (void)ws_size;
  const float* query = (const float*)d_in[0];
  const float* key   = (const float*)d_in[1];
  const float* value = (const float*)d_in[2];
  const float* Wq = (const float*)d_in[3];
  const float* bq = (const float*)d_in[4];
  const float* Wk = (const float*)d_in[5];
  const float* bk = (const float*)d_in[6];
  const float* Wv = (const float*)d_in[7];
  const float* bv = (const float*)d_in[8];
  const float* Wo = (const float*)d_in[9];
  const float* bo = (const float*)d_in[10];
  const float* rpb = (const float*)d_in[11];

  unsigned short* Wbf = (unsigned short*)d_ws;           // 4 x [128][128] bf16
  float* out_x   = (float*)d_out;                        // [64][128][56][56] fp32
  float* out_ctx = out_x + (size_t)64*CC*HW2;            // [4096][4][49][49] fp32

  wconv_kernel<<<256, 256, 0, stream>>>(Wq, Wk, Wv, Wo, Wbf);
  winattn_kernel<<<4096, 256, 0, stream>>>(query, key, value, Wbf, bq, bk, bv, bo, rpb,
                                           out_x, out_ctx);
}

// Round 6
// 336.808 us; speedup vs baseline: 3.0287x; 1.0399x over previous
//
#include <hip/hip_runtime.h>

#define NTOK 49
#define CC   128
#define NHEADS 4
#define HWW  56
#define HW2  3136
#define SCALE_F 0.17677669529663687f

typedef __attribute__((ext_vector_type(8))) short s16x8;
typedef __attribute__((ext_vector_type(4))) float f32x4;
typedef __attribute__((ext_vector_type(16))) float f32x16;

static __device__ __forceinline__ unsigned short f2bf(float f) {
  unsigned int u = __float_as_uint(f);
  u += 0x7fffu + ((u >> 16) & 1u);
  return (unsigned short)(u >> 16);
}
static __device__ __forceinline__ unsigned int pkbf(float lo, float hi) {
  return (unsigned int)f2bf(lo) | ((unsigned int)f2bf(hi) << 16);
}
// 32-col-local swizzle (keeps head column ranges disjoint), 16B-group aligned
static __device__ __forceinline__ int swz4(int row, int col) { return col ^ ((row & 3) << 3); }

union FragU { s16x8 v; unsigned int u[4]; };

__global__ void wconv_kernel(const float* __restrict__ Wq, const float* __restrict__ Wk,
                             const float* __restrict__ Wv, const float* __restrict__ Wo,
                             unsigned short* __restrict__ dst) {
  int i = blockIdx.x * 256 + threadIdx.x;
  const float* src = (i < 16384) ? Wq : (i < 32768) ? Wk : (i < 49152) ? Wv : Wo;
  float v = src[i & 16383];
  if (i < 16384) v *= SCALE_F;          // fold attention scale into Wq
  dst[i] = f2bf(v);
}

__global__ __launch_bounds__(256, 3)
void winattn_kernel(const float* __restrict__ Xq, const float* __restrict__ Xk,
                    const float* __restrict__ Xv,
                    const unsigned short* __restrict__ Wbf,
                    const float* __restrict__ bq, const float* __restrict__ bk,
                    const float* __restrict__ bv, const float* __restrict__ bo,
                    const float* __restrict__ rpb,
                    float* __restrict__ out_x,
                    float* __restrict__ out_ctx)
{
  // 51968 B total -> 3 blocks/CU
  __shared__ alignas(16) unsigned short smem[25984];
  unsigned short* Buf0 = smem;            // [49][128] raw q -> Q (in-place) -> attn-out (per-head cols)
  unsigned short* Buf1 = smem + 6272;     // [49][128] raw k -> K (in-place)
  unsigned short* VT   = smem + 12544;    // [128][56]: (h*32+d) x token, V^T
  unsigned short* Buf2 = smem + 19712;    // [49][128] raw v

  const int tid = threadIdx.x;
  const int wv  = tid >> 6;
  const int l   = tid & 63;
  const int lr  = l & 15;   // 16x16 MFMA lane row/col
  const int lg  = l >> 4;   // 16x16 MFMA k-group
  const int c31 = l & 31;   // 32x32 MFMA lane col
  const int hi  = l >> 5;   // 32x32 MFMA half

  // XCD-bijective swizzle (4096 % 8 == 0): same-band windows share an XCD L2
  const int win  = (blockIdx.x & 7) * 512 + (blockIdx.x >> 3);
  const int bimg = win >> 6;
  const int r0   = ((win >> 3) & 7) * 7;
  const int c0   = (win & 7) * 7;

  // ---- Phase 0: zero VT (padding tokens must be zero) + stage q,k,v
  {
    unsigned int* vz = (unsigned int*)VT;
    #pragma unroll
    for (int i = 0; i < 14; ++i) vz[tid + i*256] = 0u;   // 3584 dwords = 14336 B
    #pragma unroll
    for (int k = 0; k < 4; ++k) {
      int t = tid + k*256;
      if (t < 896) {                       // task = (channel ci, window-row si)
        int ci = t / 7, si = t - (t/7)*7;
        size_t off = (size_t)bimg*CC*HW2 + (size_t)ci*HW2 + (size_t)(r0+si)*HWW + c0;
        int tokb = si*7;
        #pragma unroll
        for (int sj = 0; sj < 7; ++sj) {
          int tok = tokb + sj;
          int di = tok*CC + swz4(tok, ci);
          Buf0[di] = f2bf(Xq[off+sj]);
          Buf1[di] = f2bf(Xk[off+sj]);
          Buf2[di] = f2bf(Xv[off+sj]);
        }
      }
    }
  }
  __syncthreads();

  // proj read-half: acc[mt][ntl] = src * W^T (bias folded at write)
  auto projR = [&](const unsigned short* __restrict__ src, const unsigned short* __restrict__ Wg,
                   const float* __restrict__ bias, float bscale,
                   f32x4 (&acc)[4][2], float (&bb)[2]) {
    s16x8 bfr[2][4];
    #pragma unroll
    for (int ntl = 0; ntl < 2; ++ntl) {
      int col = wv*32 + ntl*16 + lr;
      bb[ntl] = bias[col] * bscale;
      #pragma unroll
      for (int ks = 0; ks < 4; ++ks)
        bfr[ntl][ks] = *(const s16x8*)(Wg + col*CC + ks*32 + lg*8);
    }
    #pragma unroll
    for (int mt = 0; mt < 4; ++mt) {
      int ar = mt*16 + lr;
      s16x8 af[4];
      #pragma unroll
      for (int ks = 0; ks < 4; ++ks)
        af[ks] = *(const s16x8*)(src + ar*CC + swz4(ar, ks*32 + lg*8));
      #pragma unroll
      for (int ntl = 0; ntl < 2; ++ntl) {
        f32x4 a = {0.f,0.f,0.f,0.f};
        #pragma unroll
        for (int ks = 0; ks < 4; ++ks)
          a = __builtin_amdgcn_mfma_f32_16x16x32_bf16(af[ks], bfr[ntl][ks], a, 0,0,0);
        acc[mt][ntl] = a;
      }
    }
  };
  auto projW = [&](unsigned short* __restrict__ dst, f32x4 (&acc)[4][2], float (&bb)[2]) {
    #pragma unroll
    for (int mt = 0; mt < 4; ++mt) {
      #pragma unroll
      for (int ntl = 0; ntl < 2; ++ntl) {
        int col = wv*32 + ntl*16 + lr;
        #pragma unroll
        for (int r = 0; r < 4; ++r) {
          int row = mt*16 + lg*4 + r;     // C/D: row=(l>>4)*4+r, col=l&15
          if (row < NTOK)
            dst[row*CC + swz4(row, col)] = f2bf(acc[mt][ntl][r] + bb[ntl]);
        }
      }
    }
  };

  f32x4 acc[4][2]; float bb[2];
  projR(Buf0, Wbf, bq, SCALE_F, acc, bb);          // Q (scaled)
  __syncthreads();
  projW(Buf0, acc, bb);                            // Buf0 = Q
  projR(Buf1, Wbf + 16384, bk, 1.f, acc, bb);      // K
  __syncthreads();
  projW(Buf1, acc, bb);                            // Buf1 = K
  { // V projection: Buf2 -> VT
    s16x8 bfr[2][4]; float vb[2];
    #pragma unroll
    for (int ntl = 0; ntl < 2; ++ntl) {
      int col = wv*32 + ntl*16 + lr;
      vb[ntl] = bv[col];
      #pragma unroll
      for (int ks = 0; ks < 4; ++ks)
        bfr[ntl][ks] = *(const s16x8*)(Wbf + 32768 + col*CC + ks*32 + lg*8);
    }
    #pragma unroll
    for (int mt = 0; mt < 4; ++mt) {
      int ar = mt*16 + lr;
      s16x8 af[4];
      #pragma unroll
      for (int ks = 0; ks < 4; ++ks)
        af[ks] = *(const s16x8*)(Buf2 + ar*CC + swz4(ar, ks*32 + lg*8));
      #pragma unroll
      for (int ntl = 0; ntl < 2; ++ntl) {
        f32x4 a = {0.f,0.f,0.f,0.f};
        #pragma unroll
        for (int ks = 0; ks < 4; ++ks)
          a = __builtin_amdgcn_mfma_f32_16x16x32_bf16(af[ks], bfr[ntl][ks], a, 0,0,0);
        int col = wv*32 + ntl*16 + lr;
        #pragma unroll
        for (int r = 0; r < 4; ++r) {
          int row = mt*16 + lg*4 + r;   // token
          if (row < NTOK) VT[col*56 + row] = f2bf(a[r] + vb[ntl]);
        }
      }
    }
  }
  __syncthreads();

  // ---- Head section: wave wv owns head h=wv. S^T = K·Q^T via 32x32x16 MFMA.
  // Zero barriers: all state in registers / wave-local rows+cols of LDS.
  {
    const int h = wv;
    s16x8 ak[2][2], av[4];
    #pragma unroll
    for (int kt = 0; kt < 2; ++kt) {
      int krow = kt*32 + c31; if (krow > 48) krow = 48;   // clamped rows masked later
      #pragma unroll
      for (int ks = 0; ks < 2; ++ks)
        ak[kt][ks] = *(const s16x8*)(Buf1 + krow*CC + swz4(krow, h*32 + ks*16 + hi*8));
    }
    #pragma unroll
    for (int kk = 0; kk < 4; ++kk)
      av[kk] = *(const s16x8*)(VT + (h*32 + c31)*56 + kk*16 + hi*8);
    size_t cbase = ((size_t)win*NHEADS + h)*(NTOK*NTOK);

    #pragma unroll
    for (int qh = 0; qh < 2; ++qh) {
      int q = qh*32 + c31;
      int qrow = q > 48 ? 48 : q;
      s16x8 bqf[2];
      #pragma unroll
      for (int ks = 0; ks < 2; ++ks)
        bqf[ks] = *(const s16x8*)(Buf0 + qrow*CC + swz4(qrow, h*32 + ks*16 + hi*8));
      f32x16 s0 = {0,0,0,0,0,0,0,0,0,0,0,0,0,0,0,0};
      f32x16 s1 = {0,0,0,0,0,0,0,0,0,0,0,0,0,0,0,0};
      s0 = __builtin_amdgcn_mfma_f32_32x32x16_bf16(ak[0][0], bqf[0], s0, 0,0,0);
      s0 = __builtin_amdgcn_mfma_f32_32x32x16_bf16(ak[0][1], bqf[1], s0, 0,0,0);
      s1 = __builtin_amdgcn_mfma_f32_32x32x16_bf16(ak[1][0], bqf[0], s1, 0,0,0);
      s1 = __builtin_amdgcn_mfma_f32_32x32x16_bf16(ak[1][1], bqf[1], s1, 0,0,0);
      // bias + mask: entry (ktok, q); D row=(r&3)+8*(r>>2)+4*hi, col=q
      int i1 = q / 7, j1 = q - (q/7)*7;
      float mx = -1e30f;
      #pragma unroll
      for (int r = 0; r < 16; ++r) {
        int kb = (r&3) + 8*(r>>2) + 4*hi;
        { int ktok = kb;
          float s = -1e30f;
          if (q < NTOK && ktok < NTOK) {
            int i2 = ktok/7, j2 = ktok - (ktok/7)*7;
            s = s0[r] + rpb[((i1-i2+6)*13 + (j1-j2+6))*NHEADS + h];
          }
          s0[r] = s; mx = fmaxf(mx, s); }
        { int ktok = kb + 32;
          float s = -1e30f;
          if (q < NTOK && ktok < NTOK) {
            int i2 = ktok/7, j2 = ktok - (ktok/7)*7;
            s = s1[r] + rpb[((i1-i2+6)*13 + (j1-j2+6))*NHEADS + h];
          }
          s1[r] = s; mx = fmaxf(mx, s); }
      }
      mx = fmaxf(mx, __shfl_xor(mx, 32));
      float sum = 0.f;
      #pragma unroll
      for (int r = 0; r < 16; ++r) { s0[r] = __expf(s0[r]-mx); sum += s0[r]; }
      #pragma unroll
      for (int r = 0; r < 16; ++r) { s1[r] = __expf(s1[r]-mx); sum += s1[r]; }
      sum += __shfl_xor(sum, 32);
      float rinv = 1.f / sum;
      if (q < NTOK) { // ctx write [win][h][q][k]
        #pragma unroll
        for (int r = 0; r < 16; ++r) {
          int kb = (r&3) + 8*(r>>2) + 4*hi;
          out_ctx[cbase + (size_t)q*NTOK + kb] = s0[r]*rinv;
          if (kb + 32 < NTOK) out_ctx[cbase + (size_t)q*NTOK + kb + 32] = s1[r]*rinv;
        }
      }
      // pack P^T to bf16, exchange halves, feed PV (out^T = V^T · P^T)
      f32x16 pacc = {0,0,0,0,0,0,0,0,0,0,0,0,0,0,0,0};
      auto pvstep = [&](f32x16& e, const s16x8& a0, const s16x8& a1) {
        unsigned int w0m0 = pkbf(e[0],e[1]),   w0m1 = pkbf(e[2],e[3]);
        unsigned int w1m0 = pkbf(e[4],e[5]),   w1m1 = pkbf(e[6],e[7]);
        unsigned int w2m0 = pkbf(e[8],e[9]),   w2m1 = pkbf(e[10],e[11]);
        unsigned int w3m0 = pkbf(e[12],e[13]), w3m1 = pkbf(e[14],e[15]);
        unsigned int p0m0 = __shfl_xor((int)w0m0,32), p0m1 = __shfl_xor((int)w0m1,32);
        unsigned int p1m0 = __shfl_xor((int)w1m0,32), p1m1 = __shfl_xor((int)w1m1,32);
        unsigned int p2m0 = __shfl_xor((int)w2m0,32), p2m1 = __shfl_xor((int)w2m1,32);
        unsigned int p3m0 = __shfl_xor((int)w3m0,32), p3m1 = __shfl_xor((int)w3m1,32);
        FragU f;
        f.u[0] = hi ? p1m0 : w0m0;  f.u[1] = hi ? p1m1 : w0m1;
        f.u[2] = hi ? w1m0 : p0m0;  f.u[3] = hi ? w1m1 : p0m1;
        pacc = __builtin_amdgcn_mfma_f32_32x32x16_bf16(a0, f.v, pacc, 0,0,0);
        f.u[0] = hi ? p3m0 : w2m0;  f.u[1] = hi ? p3m1 : w2m1;
        f.u[2] = hi ? w3m0 : p2m0;  f.u[3] = hi ? w3m1 : p2m1;
        pacc = __builtin_amdgcn_mfma_f32_32x32x16_bf16(a1, f.v, pacc, 0,0,0);
      };
      pvstep(s0, av[0], av[1]);
      pvstep(s1, av[2], av[3]);
      if (q < NTOK) { // attn-out into dead Q cols of head h (rows q, disjoint per qh)
        #pragma unroll
        for (int r = 0; r < 16; ++r) {
          int d = (r&3) + 8*(r>>2) + 4*hi;
          Buf0[q*CC + swz4(q, h*32 + d)] = f2bf(pacc[r] * rinv);
        }
      }
    }
  }
  __syncthreads();

  { // output projection: x = attn_out @ Wo^T + bo -> [B,C,H,W] fp32
    const unsigned short* Wg = Wbf + 49152;
    s16x8 bfr[2][4]; float ob[2];
    #pragma unroll
    for (int ntl = 0; ntl < 2; ++ntl) {
      int col = wv*32 + ntl*16 + lr;
      ob[ntl] = bo[col];
      #pragma unroll
      for (int ks = 0; ks < 4; ++ks)
        bfr[ntl][ks] = *(const s16x8*)(Wg + col*CC + ks*32 + lg*8);
    }
    #pragma unroll
    for (int mt = 0; mt < 4; ++mt) {
      int ar = mt*16 + lr;
      s16x8 af[4];
      #pragma unroll
      for (int ks = 0; ks < 4; ++ks)
        af[ks] = *(const s16x8*)(Buf0 + ar*CC + swz4(ar, ks*32 + lg*8));
      #pragma unroll
      for (int ntl = 0; ntl < 2; ++ntl) {
        f32x4 a = {0.f,0.f,0.f,0.f};
        #pragma unroll
        for (int ks = 0; ks < 4; ++ks)
          a = __builtin_amdgcn_mfma_f32_16x16x32_bf16(af[ks], bfr[ntl][ks], a, 0,0,0);
        int col = wv*32 + ntl*16 + lr;
        #pragma unroll
        for (int r = 0; r < 4; ++r) {
          int row = mt*16 + lg*4 + r;
          if (row < NTOK) {
            int ii = row / 7, jj = row - (row/7)*7;
            size_t off = ((size_t)(bimg*CC + col))*HW2 + (size_t)(r0+ii)*HWW + (c0+jj);
            out_x[off] = a[r] + ob[ntl];
          }
        }
      }
    }
  }
}

extern "C" void kernel_launch(void* const* d_in, const int* in_sizes, int n_in,
                              void* d_out, int out_size, void* d_ws, size_t ws_size,
                              hipStream_t stream) {
  (void)in_sizes; (void)n_in; (void)out_size; (void)ws_size;
  const float* query = (const float*)d_in[0];
  const float* key   = (const float*)d_in[1];
  const float* value = (const float*)d_in[2];
  const float* Wq = (const float*)d_in[3];
  const float* bq = (const float*)d_in[4];
  const float* Wk = (const float*)d_in[5];
  const float* bk = (const float*)d_in[6];
  const float* Wv = (const float*)d_in[7];
  const float* bv = (const float*)d_in[8];
  const float* Wo = (const float*)d_in[9];
  const float* bo = (const float*)d_in[10];
  const float* rpb = (const float*)d_in[11];

  unsigned short* Wbf = (unsigned short*)d_ws;           // 4 x [128][128] bf16
  float* out_x   = (float*)d_out;                        // [64][128][56][56] fp32
  float* out_ctx = out_x + (size_t)64*CC*HW2;            // [4096][4][49][49] fp32

  wconv_kernel<<<256, 256, 0, stream>>>(Wq, Wk, Wv, Wo, Wbf);
  winattn_kernel<<<4096, 256, 0, stream>>>(query, key, value, Wbf, bq, bk, bv, bo, rpb,
                                           out_x, out_ctx);
}

// Round 7
// 314.133 us; speedup vs baseline: 3.2473x; 1.0722x over previous
//
#include <hip/hip_runtime.h>

#define NTOK 49
#define CC   128
#define NHEADS 4
#define HWW  56
#define HW2  3136
#define SCALE_F 0.17677669529663687f

typedef __attribute__((ext_vector_type(8))) short s16x8;
typedef __attribute__((ext_vector_type(4))) float f32x4;
typedef __attribute__((ext_vector_type(16))) float f32x16;

static __device__ __forceinline__ unsigned short f2bf(float f) {
  unsigned int u = __float_as_uint(f);
  u += 0x7fffu + ((u >> 16) & 1u);
  return (unsigned short)(u >> 16);
}
static __device__ __forceinline__ float bf2f(unsigned short h) {
  return __uint_as_float(((unsigned int)h) << 16);
}
static __device__ __forceinline__ unsigned int pkbf(float lo, float hi) {
  return (unsigned int)f2bf(lo) | ((unsigned int)f2bf(hi) << 16);
}
// 32-col-local swizzle (keeps head column ranges disjoint), 16B-group aligned
static __device__ __forceinline__ int swz4(int row, int col) { return col ^ ((row & 3) << 3); }

union FragU { s16x8 v; unsigned int u[4]; };

__global__ void wconv_kernel(const float* __restrict__ Wq, const float* __restrict__ Wk,
                             const float* __restrict__ Wv, const float* __restrict__ Wo,
                             unsigned short* __restrict__ dst) {
  int i = blockIdx.x * 256 + threadIdx.x;
  const float* src = (i < 16384) ? Wq : (i < 32768) ? Wk : (i < 49152) ? Wv : Wo;
  float v = src[i & 16383];
  if (i < 16384) v *= SCALE_F;          // fold attention scale into Wq
  dst[i] = f2bf(v);
}

__global__ __launch_bounds__(256, 3)
void winattn_kernel(const float* __restrict__ Xq, const float* __restrict__ Xk,
                    const float* __restrict__ Xv,
                    const unsigned short* __restrict__ Wbf,
                    const float* __restrict__ bq, const float* __restrict__ bk,
                    const float* __restrict__ bv, const float* __restrict__ bo,
                    const float* __restrict__ rpb,
                    float* __restrict__ out_x,
                    float* __restrict__ out_ctx)
{
  // 51968 B total -> 3 blocks/CU
  __shared__ alignas(16) unsigned short smem[25984];
  unsigned short* Buf0 = smem;            // [49][128] raw q -> Q (in-place) -> attn-out (per-head cols)
  unsigned short* Buf1 = smem + 6272;     // [49][128] raw k -> K (in-place)
  unsigned short* VT   = smem + 12544;    // [128][56]: (h*32+d) x token, V^T
  unsigned short* Buf2 = smem + 19712;    // [49][128] raw v -> P bounce [4][32*49] bf16

  const int tid = threadIdx.x;
  const int wv  = tid >> 6;
  const int l   = tid & 63;
  const int lr  = l & 15;   // 16x16 MFMA lane row/col
  const int lg  = l >> 4;   // 16x16 MFMA k-group
  const int c31 = l & 31;   // 32x32 MFMA lane col
  const int hi  = l >> 5;   // 32x32 MFMA half

  // XCD-bijective swizzle (4096 % 8 == 0): same-band windows share an XCD L2
  const int win  = (blockIdx.x & 7) * 512 + (blockIdx.x >> 3);
  const int bimg = win >> 6;
  const int r0   = ((win >> 3) & 7) * 7;
  const int c0   = (win & 7) * 7;

  // ---- Phase 0: zero VT (padding tokens must be zero) + stage q,k,v
  // pixel-major lanes: a wave's 64 addresses cover 7-float runs (~10 lines/inst)
  {
    unsigned int* vz = (unsigned int*)VT;
    #pragma unroll
    for (int i = 0; i < 14; ++i) vz[tid + i*256] = 0u;   // 3584 dwords = 14336 B
    int s = tid & 63, g = tid >> 6;
    if (s < NTOK) {
      int si = s / 7, sj = s - si*7;
      size_t base = (size_t)bimg*CC*HW2 + (size_t)(r0+si)*HWW + (c0+sj);
      int rb = s * CC;
      #pragma unroll 8
      for (int cc = 0; cc < 32; ++cc) {
        int ci = g*32 + cc;
        size_t off = base + (size_t)ci * HW2;
        int di = rb + swz4(s, ci);
        Buf0[di] = f2bf(Xq[off]);
        Buf1[di] = f2bf(Xk[off]);
        Buf2[di] = f2bf(Xv[off]);
      }
    }
  }
  __syncthreads();

  // proj read-half: acc[mt][ntl] = src * W^T (bias folded at write)
  auto projR = [&](const unsigned short* __restrict__ src, const unsigned short* __restrict__ Wg,
                   const float* __restrict__ bias, float bscale,
                   f32x4 (&acc)[4][2], float (&bb)[2]) {
    s16x8 bfr[2][4];
    #pragma unroll
    for (int ntl = 0; ntl < 2; ++ntl) {
      int col = wv*32 + ntl*16 + lr;
      bb[ntl] = bias[col] * bscale;
      #pragma unroll
      for (int ks = 0; ks < 4; ++ks)
        bfr[ntl][ks] = *(const s16x8*)(Wg + col*CC + ks*32 + lg*8);
    }
    #pragma unroll
    for (int mt = 0; mt < 4; ++mt) {
      int ar = mt*16 + lr;
      s16x8 af[4];
      #pragma unroll
      for (int ks = 0; ks < 4; ++ks)
        af[ks] = *(const s16x8*)(src + ar*CC + swz4(ar, ks*32 + lg*8));
      #pragma unroll
      for (int ntl = 0; ntl < 2; ++ntl) {
        f32x4 a = {0.f,0.f,0.f,0.f};
        #pragma unroll
        for (int ks = 0; ks < 4; ++ks)
          a = __builtin_amdgcn_mfma_f32_16x16x32_bf16(af[ks], bfr[ntl][ks], a, 0,0,0);
        acc[mt][ntl] = a;
      }
    }
  };
  auto projW = [&](unsigned short* __restrict__ dst, f32x4 (&acc)[4][2], float (&bb)[2]) {
    #pragma unroll
    for (int mt = 0; mt < 4; ++mt) {
      #pragma unroll
      for (int ntl = 0; ntl < 2; ++ntl) {
        int col = wv*32 + ntl*16 + lr;
        #pragma unroll
        for (int r = 0; r < 4; ++r) {
          int row = mt*16 + lg*4 + r;     // C/D: row=(l>>4)*4+r, col=l&15
          if (row < NTOK)
            dst[row*CC + swz4(row, col)] = f2bf(acc[mt][ntl][r] + bb[ntl]);
        }
      }
    }
  };

  f32x4 acc[4][2]; float bb[2];
  projR(Buf0, Wbf, bq, SCALE_F, acc, bb);          // Q (scaled)
  __syncthreads();
  projW(Buf0, acc, bb);                            // Buf0 = Q
  projR(Buf1, Wbf + 16384, bk, 1.f, acc, bb);      // K
  __syncthreads();
  projW(Buf1, acc, bb);                            // Buf1 = K
  { // V projection: Buf2 -> VT
    s16x8 bfr[2][4]; float vb[2];
    #pragma unroll
    for (int ntl = 0; ntl < 2; ++ntl) {
      int col = wv*32 + ntl*16 + lr;
      vb[ntl] = bv[col];
      #pragma unroll
      for (int ks = 0; ks < 4; ++ks)
        bfr[ntl][ks] = *(const s16x8*)(Wbf + 32768 + col*CC + ks*32 + lg*8);
    }
    #pragma unroll
    for (int mt = 0; mt < 4; ++mt) {
      int ar = mt*16 + lr;
      s16x8 af[4];
      #pragma unroll
      for (int ks = 0; ks < 4; ++ks)
        af[ks] = *(const s16x8*)(Buf2 + ar*CC + swz4(ar, ks*32 + lg*8));
      #pragma unroll
      for (int ntl = 0; ntl < 2; ++ntl) {
        f32x4 a = {0.f,0.f,0.f,0.f};
        #pragma unroll
        for (int ks = 0; ks < 4; ++ks)
          a = __builtin_amdgcn_mfma_f32_16x16x32_bf16(af[ks], bfr[ntl][ks], a, 0,0,0);
        int col = wv*32 + ntl*16 + lr;
        #pragma unroll
        for (int r = 0; r < 4; ++r) {
          int row = mt*16 + lg*4 + r;   // token
          if (row < NTOK) VT[col*56 + row] = f2bf(a[r] + vb[ntl]);
        }
      }
    }
  }
  __syncthreads();

  // ---- Head section: wave wv owns head h=wv. S^T = K·Q^T via 32x32x16 MFMA.
  // Buf2 is dead (V projected) -> reuse as per-head P bounce: [h][32 q][49 k] bf16.
  {
    const int h = wv;
    s16x8 ak[2][2], av[4];
    #pragma unroll
    for (int kt = 0; kt < 2; ++kt) {
      int krow = kt*32 + c31; if (krow > 48) krow = 48;   // clamped rows masked later
      #pragma unroll
      for (int ks = 0; ks < 2; ++ks)
        ak[kt][ks] = *(const s16x8*)(Buf1 + krow*CC + swz4(krow, h*32 + ks*16 + hi*8));
    }
    #pragma unroll
    for (int kk = 0; kk < 4; ++kk)
      av[kk] = *(const s16x8*)(VT + (h*32 + c31)*56 + kk*16 + hi*8);
    size_t cbase = ((size_t)win*NHEADS + h)*(NTOK*NTOK);
    unsigned short* PL = Buf2 + h*1568;    // wave-local bounce [32][49] bf16

    #pragma unroll
    for (int qh = 0; qh < 2; ++qh) {
      int q = qh*32 + c31;
      int qrow = q > 48 ? 48 : q;
      s16x8 bqf[2];
      #pragma unroll
      for (int ks = 0; ks < 2; ++ks)
        bqf[ks] = *(const s16x8*)(Buf0 + qrow*CC + swz4(qrow, h*32 + ks*16 + hi*8));
      f32x16 s0 = {0,0,0,0,0,0,0,0,0,0,0,0,0,0,0,0};
      f32x16 s1 = {0,0,0,0,0,0,0,0,0,0,0,0,0,0,0,0};
      s0 = __builtin_amdgcn_mfma_f32_32x32x16_bf16(ak[0][0], bqf[0], s0, 0,0,0);
      s0 = __builtin_amdgcn_mfma_f32_32x32x16_bf16(ak[0][1], bqf[1], s0, 0,0,0);
      s1 = __builtin_amdgcn_mfma_f32_32x32x16_bf16(ak[1][0], bqf[0], s1, 0,0,0);
      s1 = __builtin_amdgcn_mfma_f32_32x32x16_bf16(ak[1][1], bqf[1], s1, 0,0,0);
      // bias + mask: entry (ktok, q); D row=(r&3)+8*(r>>2)+4*hi, col=q
      int i1 = q / 7, j1 = q - (q/7)*7;
      float mx = -1e30f;
      #pragma unroll
      for (int r = 0; r < 16; ++r) {
        int kb = (r&3) + 8*(r>>2) + 4*hi;
        { int ktok = kb;
          float s = -1e30f;
          if (q < NTOK && ktok < NTOK) {
            int i2 = ktok/7, j2 = ktok - (ktok/7)*7;
            s = s0[r] + rpb[((i1-i2+6)*13 + (j1-j2+6))*NHEADS + h];
          }
          s0[r] = s; mx = fmaxf(mx, s); }
        { int ktok = kb + 32;
          float s = -1e30f;
          if (q < NTOK && ktok < NTOK) {
            int i2 = ktok/7, j2 = ktok - (ktok/7)*7;
            s = s1[r] + rpb[((i1-i2+6)*13 + (j1-j2+6))*NHEADS + h];
          }
          s1[r] = s; mx = fmaxf(mx, s); }
      }
      mx = fmaxf(mx, __shfl_xor(mx, 32));
      float sum = 0.f;
      #pragma unroll
      for (int r = 0; r < 16; ++r) { s0[r] = __expf(s0[r]-mx); sum += s0[r]; }
      #pragma unroll
      for (int r = 0; r < 16; ++r) { s1[r] = __expf(s1[r]-mx); sum += s1[r]; }
      sum += __shfl_xor(sum, 32);
      float rinv = 1.f / sum;
      #pragma unroll
      for (int r = 0; r < 16; ++r) { s0[r] *= rinv; s1[r] *= rinv; }   // normalize in-register
      // stash normalized P^T half into wave-local LDS (for coalesced ctx dump)
      if (q < NTOK) {
        #pragma unroll
        for (int r = 0; r < 16; ++r) {
          int kb = (r&3) + 8*(r>>2) + 4*hi;
          PL[c31*NTOK + kb] = f2bf(s0[r]);
          if (kb + 32 < NTOK) PL[c31*NTOK + kb + 32] = f2bf(s1[r]);
        }
      }
      // PV: pack P^T bf16, exchange halves, out^T = V^T · P^T (P already normalized)
      f32x16 pacc = {0,0,0,0,0,0,0,0,0,0,0,0,0,0,0,0};
      auto pvstep = [&](f32x16& e, const s16x8& a0, const s16x8& a1) {
        unsigned int w0m0 = pkbf(e[0],e[1]),   w0m1 = pkbf(e[2],e[3]);
        unsigned int w1m0 = pkbf(e[4],e[5]),   w1m1 = pkbf(e[6],e[7]);
        unsigned int w2m0 = pkbf(e[8],e[9]),   w2m1 = pkbf(e[10],e[11]);
        unsigned int w3m0 = pkbf(e[12],e[13]), w3m1 = pkbf(e[14],e[15]);
        unsigned int p0m0 = __shfl_xor((int)w0m0,32), p0m1 = __shfl_xor((int)w0m1,32);
        unsigned int p1m0 = __shfl_xor((int)w1m0,32), p1m1 = __shfl_xor((int)w1m1,32);
        unsigned int p2m0 = __shfl_xor((int)w2m0,32), p2m1 = __shfl_xor((int)w2m1,32);
        unsigned int p3m0 = __shfl_xor((int)w3m0,32), p3m1 = __shfl_xor((int)w3m1,32);
        FragU f;
        f.u[0] = hi ? p1m0 : w0m0;  f.u[1] = hi ? p1m1 : w0m1;
        f.u[2] = hi ? w1m0 : p0m0;  f.u[3] = hi ? w1m1 : p0m1;
        pacc = __builtin_amdgcn_mfma_f32_32x32x16_bf16(a0, f.v, pacc, 0,0,0);
        f.u[0] = hi ? p3m0 : w2m0;  f.u[1] = hi ? p3m1 : w2m1;
        f.u[2] = hi ? w3m0 : p2m0;  f.u[3] = hi ? w3m1 : p2m1;
        pacc = __builtin_amdgcn_mfma_f32_32x32x16_bf16(a1, f.v, pacc, 0,0,0);
      };
      pvstep(s0, av[0], av[1]);
      pvstep(s1, av[2], av[3]);
      // coalesced ctx dump: PL is linear in idx = q'*49 + k (wave-local, compiler
      // inserts the ds write->read wait)
      {
        const int cnt = (qh == 0) ? 32*NTOK : (NTOK-32)*NTOK;
        size_t gb = cbase + (size_t)qh*32*NTOK;
        #pragma unroll
        for (int base = 0; base < cnt; base += 64) {
          int idx = base + l;
          if (idx < cnt) out_ctx[gb + idx] = bf2f(PL[idx]);
        }
      }
      if (q < NTOK) { // attn-out into dead Q cols of head h (rows q, disjoint per qh)
        #pragma unroll
        for (int r = 0; r < 16; ++r) {
          int d = (r&3) + 8*(r>>2) + 4*hi;
          Buf0[q*CC + swz4(q, h*32 + d)] = f2bf(pacc[r]);
        }
      }
    }
  }
  __syncthreads();

  { // output projection: x = attn_out @ Wo^T + bo -> [B,C,H,W] fp32
    const unsigned short* Wg = Wbf + 49152;
    s16x8 bfr[2][4]; float ob[2];
    #pragma unroll
    for (int ntl = 0; ntl < 2; ++ntl) {
      int col = wv*32 + ntl*16 + lr;
      ob[ntl] = bo[col];
      #pragma unroll
      for (int ks = 0; ks < 4; ++ks)
        bfr[ntl][ks] = *(const s16x8*)(Wg + col*CC + ks*32 + lg*8);
    }
    #pragma unroll
    for (int mt = 0; mt < 4; ++mt) {
      int ar = mt*16 + lr;
      s16x8 af[4];
      #pragma unroll
      for (int ks = 0; ks < 4; ++ks)
        af[ks] = *(const s16x8*)(Buf0 + ar*CC + swz4(ar, ks*32 + lg*8));
      #pragma unroll
      for (int ntl = 0; ntl < 2; ++ntl) {
        f32x4 a = {0.f,0.f,0.f,0.f};
        #pragma unroll
        for (int ks = 0; ks < 4; ++ks)
          a = __builtin_amdgcn_mfma_f32_16x16x32_bf16(af[ks], bfr[ntl][ks], a, 0,0,0);
        int col = wv*32 + ntl*16 + lr;
        #pragma unroll
        for (int r = 0; r < 4; ++r) {
          int row = mt*16 + lg*4 + r;
          if (row < NTOK) {
            int ii = row / 7, jj = row - (row/7)*7;
            size_t off = ((size_t)(bimg*CC + col))*HW2 + (size_t)(r0+ii)*HWW + (c0+jj);
            out_x[off] = a[r] + ob[ntl];
          }
        }
      }
    }
  }
}

extern "C" void kernel_launch(void* const* d_in, const int* in_sizes, int n_in,
                              void* d_out, int out_size, void* d_ws, size_t ws_size,
                              hipStream_t stream) {
  (void)in_sizes; (void)n_in; (void)out_size; (void)ws_size;
  const float* query = (const float*)d_in[0];
  const float* key   = (const float*)d_in[1];
  const float* value = (const float*)d_in[2];
  const float* Wq = (const float*)d_in[3];
  const float* bq = (const float*)d_in[4];
  const float* Wk = (const float*)d_in[5];
  const float* bk = (const float*)d_in[6];
  const float* Wv = (const float*)d_in[7];
  const float* bv = (const float*)d_in[8];
  const float* Wo = (const float*)d_in[9];
  const float* bo = (const float*)d_in[10];
  const float* rpb = (const float*)d_in[11];

  unsigned short* Wbf = (unsigned short*)d_ws;           // 4 x [128][128] bf16
  float* out_x   = (float*)d_out;                        // [64][128][56][56] fp32
  float* out_ctx = out_x + (size_t)64*CC*HW2;            // [4096][4][49][49] fp32

  wconv_kernel<<<256, 256, 0, stream>>>(Wq, Wk, Wv, Wo, Wbf);
  winattn_kernel<<<4096, 256, 0, stream>>>(query, key, value, Wbf, bq, bk, bv, bo, rpb,
                                           out_x, out_ctx);
}

// Round 8
// 264.640 us; speedup vs baseline: 3.8546x; 1.1870x over previous
//
#include <hip/hip_runtime.h>

#define NTOK 49
#define CC   128
#define NHEADS 4
#define HWW  56
#define HW2  3136
#define SCALE_F 0.17677669529663687f

typedef __attribute__((ext_vector_type(8))) short s16x8;
typedef __attribute__((ext_vector_type(4))) float f32x4;
typedef __attribute__((ext_vector_type(16))) float f32x16;
typedef __attribute__((ext_vector_type(2))) unsigned int u32x2;

static __device__ __forceinline__ unsigned short f2bf(float f) {
  unsigned int u = __float_as_uint(f);
  u += 0x7fffu + ((u >> 16) & 1u);
  return (unsigned short)(u >> 16);
}
static __device__ __forceinline__ float bf2f(unsigned short h) {
  return __uint_as_float(((unsigned int)h) << 16);
}
static __device__ __forceinline__ unsigned int pkbf(float lo, float hi) {
  return (unsigned int)f2bf(lo) | ((unsigned int)f2bf(hi) << 16);
}
// full-row bijective swizzle, flips col bits 3-5 by row -> 8 bank-slot spread,
// keeps 8-elem (16B) groups contiguous. Used by ALL writers/readers of Buf0/1/2.
static __device__ __forceinline__ int swz8(int row, int col) { return col ^ ((row & 7) << 3); }

union FragU { s16x8 v; unsigned int u[4]; };

// prep: weights -> bf16 (scale folded into Wq) + bias table Biasg[h][k][q]
__global__ void prep_kernel(const float* __restrict__ Wq, const float* __restrict__ Wk,
                            const float* __restrict__ Wv, const float* __restrict__ Wo,
                            const float* __restrict__ rpb,
                            unsigned short* __restrict__ dstW, float* __restrict__ dstB) {
  int i = blockIdx.x * 256 + threadIdx.x;
  if (i < 65536) {
    const float* src = (i < 16384) ? Wq : (i < 32768) ? Wk : (i < 49152) ? Wv : Wo;
    float v = src[i & 16383];
    if (i < 16384) v *= SCALE_F;
    dstW[i] = f2bf(v);
  } else {
    int j = i - 65536;
    if (j < NHEADS*NTOK*NTOK) {
      int h = j / (NTOK*NTOK), rem = j - h*(NTOK*NTOK);
      int k = rem / NTOK, q = rem - k*NTOK;
      int qi = q/7, qj = q - qi*7, ki = k/7, kj = k - ki*7;
      dstB[j] = rpb[((qi-ki+6)*13 + (qj-kj+6))*NHEADS + h];
    }
  }
}

__global__ __launch_bounds__(256, 3)
void winattn_kernel(const float* __restrict__ Xq, const float* __restrict__ Xk,
                    const float* __restrict__ Xv,
                    const unsigned short* __restrict__ Wbf,
                    const float* __restrict__ Biasg,
                    const float* __restrict__ bq, const float* __restrict__ bk,
                    const float* __restrict__ bv, const float* __restrict__ bo,
                    float* __restrict__ out_x,
                    float* __restrict__ out_ctx)
{
  // 51968 B total -> 3 blocks/CU
  __shared__ alignas(16) unsigned short smem[25984];
  unsigned short* Buf0 = smem;            // [49][128] raw q -> Q -> attn-out (swz8)
  unsigned short* Buf1 = smem + 6272;     // [49][128] raw k -> K (swz8)
  unsigned short* VT   = smem + 12544;    // [128][56]: (h*32+d) x token, V^T
  unsigned short* Buf2 = smem + 19712;    // [49][128] raw v (swz8) -> P bounce [4][1568]
  float* Obnc = (float*)(smem + 12544);   // epilogue bounce [4 waves][32ch][49tok] stride 50

  const int tid = threadIdx.x;
  const int wv  = tid >> 6;
  const int l   = tid & 63;
  const int lr  = l & 15;   // 16x16 MFMA lane row/col
  const int lg  = l >> 4;   // 16x16 MFMA k-group
  const int c31 = l & 31;   // 32x32 MFMA lane col
  const int hi  = l >> 5;   // 32x32 MFMA half

  // XCD-bijective swizzle (4096 % 8 == 0): same-band windows share an XCD L2
  const int win  = (blockIdx.x & 7) * 512 + (blockIdx.x >> 3);
  const int bimg = win >> 6;
  const int r0   = ((win >> 3) & 7) * 7;
  const int c0   = (win & 7) * 7;

  // ---- Phase 0: zero VT + stage q,k,v (lane=token: ~10 lines/inst global;
  // b64 LDS stores, 4 channels/lane: 24 stores vs 96, ~6-way banks)
  {
    unsigned int* vz = (unsigned int*)VT;
    #pragma unroll
    for (int i = 0; i < 14; ++i) vz[tid + i*256] = 0u;   // 14336 B
    int s = tid & 63, g = tid >> 6;
    if (s < NTOK) {
      int si = s / 7, sj = s - si*7;
      size_t base = (size_t)bimg*CC*HW2 + (size_t)(r0+si)*HWW + (c0+sj);
      #pragma unroll 4
      for (int cp = 0; cp < 8; ++cp) {
        int ci = g*32 + cp*4;
        size_t off = base + (size_t)ci * HW2;
        float q0 = Xq[off], q1 = Xq[off+HW2], q2 = Xq[off+2*HW2], q3 = Xq[off+3*HW2];
        float k0 = Xk[off], k1 = Xk[off+HW2], k2 = Xk[off+2*HW2], k3 = Xk[off+3*HW2];
        float v0 = Xv[off], v1 = Xv[off+HW2], v2 = Xv[off+2*HW2], v3 = Xv[off+3*HW2];
        int di = s*CC + swz8(s, ci);                  // 4-aligned (swz8 keeps bits 0-2)
        u32x2 pq = {pkbf(q0,q1), pkbf(q2,q3)};
        u32x2 pk = {pkbf(k0,k1), pkbf(k2,k3)};
        u32x2 pv = {pkbf(v0,v1), pkbf(v2,v3)};
        *(u32x2*)(Buf0 + di) = pq;
        *(u32x2*)(Buf1 + di) = pk;
        *(u32x2*)(Buf2 + di) = pv;
      }
    }
  }
  __syncthreads();

  // proj read-half: acc[mt][ntl] = src * W^T (bias folded at write)
  auto projR = [&](const unsigned short* __restrict__ src, const unsigned short* __restrict__ Wg,
                   const float* __restrict__ bias, float bscale,
                   f32x4 (&acc)[4][2], float (&bb)[2]) {
    s16x8 bfr[2][4];
    #pragma unroll
    for (int ntl = 0; ntl < 2; ++ntl) {
      int col = wv*32 + ntl*16 + lr;
      bb[ntl] = bias[col] * bscale;
      #pragma unroll
      for (int ks = 0; ks < 4; ++ks)
        bfr[ntl][ks] = *(const s16x8*)(Wg + col*CC + ks*32 + lg*8);
    }
    #pragma unroll
    for (int mt = 0; mt < 4; ++mt) {
      int ar = mt*16 + lr;
      s16x8 af[4];
      #pragma unroll
      for (int ks = 0; ks < 4; ++ks)
        af[ks] = *(const s16x8*)(src + ar*CC + swz8(ar, ks*32 + lg*8));
      #pragma unroll
      for (int ntl = 0; ntl < 2; ++ntl) {
        f32x4 a = {0.f,0.f,0.f,0.f};
        #pragma unroll
        for (int ks = 0; ks < 4; ++ks)
          a = __builtin_amdgcn_mfma_f32_16x16x32_bf16(af[ks], bfr[ntl][ks], a, 0,0,0);
        acc[mt][ntl] = a;
      }
    }
  };
  auto projW = [&](unsigned short* __restrict__ dst, f32x4 (&acc)[4][2], float (&bb)[2]) {
    #pragma unroll
    for (int mt = 0; mt < 4; ++mt) {
      #pragma unroll
      for (int ntl = 0; ntl < 2; ++ntl) {
        int col = wv*32 + ntl*16 + lr;
        #pragma unroll
        for (int r = 0; r < 4; ++r) {
          int row = mt*16 + lg*4 + r;     // C/D: row=(l>>4)*4+r, col=l&15
          if (row < NTOK)
            dst[row*CC + swz8(row, col)] = f2bf(acc[mt][ntl][r] + bb[ntl]);
        }
      }
    }
  };

  f32x4 acc[4][2]; float bb[2];
  projR(Buf0, Wbf, bq, SCALE_F, acc, bb);          // Q (scaled)
  __syncthreads();
  projW(Buf0, acc, bb);                            // Buf0 = Q
  projR(Buf1, Wbf + 16384, bk, 1.f, acc, bb);      // K
  __syncthreads();
  projW(Buf1, acc, bb);                            // Buf1 = K
  { // V projection: Buf2 -> VT
    s16x8 bfr[2][4]; float vb[2];
    #pragma unroll
    for (int ntl = 0; ntl < 2; ++ntl) {
      int col = wv*32 + ntl*16 + lr;
      vb[ntl] = bv[col];
      #pragma unroll
      for (int ks = 0; ks < 4; ++ks)
        bfr[ntl][ks] = *(const s16x8*)(Wbf + 32768 + col*CC + ks*32 + lg*8);
    }
    #pragma unroll
    for (int mt = 0; mt < 4; ++mt) {
      int ar = mt*16 + lr;
      s16x8 af[4];
      #pragma unroll
      for (int ks = 0; ks < 4; ++ks)
        af[ks] = *(const s16x8*)(Buf2 + ar*CC + swz8(ar, ks*32 + lg*8));
      #pragma unroll
      for (int ntl = 0; ntl < 2; ++ntl) {
        f32x4 a = {0.f,0.f,0.f,0.f};
        #pragma unroll
        for (int ks = 0; ks < 4; ++ks)
          a = __builtin_amdgcn_mfma_f32_16x16x32_bf16(af[ks], bfr[ntl][ks], a, 0,0,0);
        int col = wv*32 + ntl*16 + lr;
        #pragma unroll
        for (int r = 0; r < 4; ++r) {
          int row = mt*16 + lg*4 + r;   // token
          if (row < NTOK) VT[col*56 + row] = f2bf(a[r] + vb[ntl]);
        }
      }
    }
  }
  __syncthreads();

  // ---- Head section: wave wv owns head h=wv. S^T = K·Q^T via 32x32x16 MFMA.
  {
    const int h = wv;
    const float* Bh = Biasg + h*(NTOK*NTOK);   // [k][q], lane-consecutive in q
    s16x8 ak[2][2], av[4];
    #pragma unroll
    for (int kt = 0; kt < 2; ++kt) {
      int krow = kt*32 + c31; if (krow > 48) krow = 48;   // clamped rows masked later
      #pragma unroll
      for (int ks = 0; ks < 2; ++ks)
        ak[kt][ks] = *(const s16x8*)(Buf1 + krow*CC + swz8(krow, h*32 + ks*16 + hi*8));
    }
    #pragma unroll
    for (int kk = 0; kk < 4; ++kk)
      av[kk] = *(const s16x8*)(VT + (h*32 + c31)*56 + kk*16 + hi*8);
    size_t cbase = ((size_t)win*NHEADS + h)*(NTOK*NTOK);
    unsigned short* PL = Buf2 + h*1568;    // wave-local bounce [32][49] bf16

    #pragma unroll
    for (int qh = 0; qh < 2; ++qh) {
      int q = qh*32 + c31;
      int qrow = q > 48 ? 48 : q;
      s16x8 bqf[2];
      #pragma unroll
      for (int ks = 0; ks < 2; ++ks)
        bqf[ks] = *(const s16x8*)(Buf0 + qrow*CC + swz8(qrow, h*32 + ks*16 + hi*8));
      f32x16 s0 = {0,0,0,0,0,0,0,0,0,0,0,0,0,0,0,0};
      f32x16 s1 = {0,0,0,0,0,0,0,0,0,0,0,0,0,0,0,0};
      s0 = __builtin_amdgcn_mfma_f32_32x32x16_bf16(ak[0][0], bqf[0], s0, 0,0,0);
      s0 = __builtin_amdgcn_mfma_f32_32x32x16_bf16(ak[0][1], bqf[1], s0, 0,0,0);
      s1 = __builtin_amdgcn_mfma_f32_32x32x16_bf16(ak[1][0], bqf[0], s1, 0,0,0);
      s1 = __builtin_amdgcn_mfma_f32_32x32x16_bf16(ak[1][1], bqf[1], s1, 0,0,0);
      // bias (precomputed table) + mask; D row=(r&3)+8*(r>>2)+4*hi, col=q
      float mx = -1e30f;
      #pragma unroll
      for (int r = 0; r < 16; ++r) {
        int kb = (r&3) + 8*(r>>2) + 4*hi;
        float v0 = -1e30f, v1 = -1e30f;
        if (q < NTOK) {
          v0 = s0[r] + Bh[kb*NTOK + q];
          if (kb + 32 < NTOK) v1 = s1[r] + Bh[(kb+32)*NTOK + q];
        }
        s0[r] = v0; mx = fmaxf(mx, v0);
        s1[r] = v1; mx = fmaxf(mx, v1);
      }
      mx = fmaxf(mx, __shfl_xor(mx, 32));
      float sum = 0.f;
      #pragma unroll
      for (int r = 0; r < 16; ++r) { s0[r] = __expf(s0[r]-mx); sum += s0[r]; }
      #pragma unroll
      for (int r = 0; r < 16; ++r) { s1[r] = __expf(s1[r]-mx); sum += s1[r]; }
      sum += __shfl_xor(sum, 32);
      float rinv = 1.f / sum;
      #pragma unroll
      for (int r = 0; r < 16; ++r) { s0[r] *= rinv; s1[r] *= rinv; }   // normalize
      // stash normalized P^T half into wave-local LDS (coalesced ctx dump)
      if (q < NTOK) {
        #pragma unroll
        for (int r = 0; r < 16; ++r) {
          int kb = (r&3) + 8*(r>>2) + 4*hi;
          PL[c31*NTOK + kb] = f2bf(s0[r]);
          if (kb + 32 < NTOK) PL[c31*NTOK + kb + 32] = f2bf(s1[r]);
        }
      }
      // PV: pack P^T bf16, exchange halves, out^T = V^T · P^T
      f32x16 pacc = {0,0,0,0,0,0,0,0,0,0,0,0,0,0,0,0};
      auto pvstep = [&](f32x16& e, const s16x8& a0, const s16x8& a1) {
        unsigned int w0m0 = pkbf(e[0],e[1]),   w0m1 = pkbf(e[2],e[3]);
        unsigned int w1m0 = pkbf(e[4],e[5]),   w1m1 = pkbf(e[6],e[7]);
        unsigned int w2m0 = pkbf(e[8],e[9]),   w2m1 = pkbf(e[10],e[11]);
        unsigned int w3m0 = pkbf(e[12],e[13]), w3m1 = pkbf(e[14],e[15]);
        unsigned int p0m0 = __shfl_xor((int)w0m0,32), p0m1 = __shfl_xor((int)w0m1,32);
        unsigned int p1m0 = __shfl_xor((int)w1m0,32), p1m1 = __shfl_xor((int)w1m1,32);
        unsigned int p2m0 = __shfl_xor((int)w2m0,32), p2m1 = __shfl_xor((int)w2m1,32);
        unsigned int p3m0 = __shfl_xor((int)w3m0,32), p3m1 = __shfl_xor((int)w3m1,32);
        FragU f;
        f.u[0] = hi ? p1m0 : w0m0;  f.u[1] = hi ? p1m1 : w0m1;
        f.u[2] = hi ? w1m0 : p0m0;  f.u[3] = hi ? w1m1 : p0m1;
        pacc = __builtin_amdgcn_mfma_f32_32x32x16_bf16(a0, f.v, pacc, 0,0,0);
        f.u[0] = hi ? p3m0 : w2m0;  f.u[1] = hi ? p3m1 : w2m1;
        f.u[2] = hi ? w3m0 : p2m0;  f.u[3] = hi ? w3m1 : p2m1;
        pacc = __builtin_amdgcn_mfma_f32_32x32x16_bf16(a1, f.v, pacc, 0,0,0);
      };
      pvstep(s0, av[0], av[1]);
      pvstep(s1, av[2], av[3]);
      { // coalesced ctx dump (wave-local)
        const int cnt = (qh == 0) ? 32*NTOK : (NTOK-32)*NTOK;
        size_t gb = cbase + (size_t)qh*32*NTOK;
        #pragma unroll
        for (int base = 0; base < cnt; base += 64) {
          int idx = base + l;
          if (idx < cnt) out_ctx[gb + idx] = bf2f(PL[idx]);
        }
      }
      if (q < NTOK) { // attn-out into dead Q cols (global bijective swz8 -> no collisions)
        #pragma unroll
        for (int r = 0; r < 16; ++r) {
          int d = (r&3) + 8*(r>>2) + 4*hi;
          Buf0[q*CC + swz8(q, h*32 + d)] = f2bf(pacc[r]);
        }
      }
    }
  }
  __syncthreads();

  { // output projection: x = attn_out @ Wo^T + bo, via LDS bounce (VT/Buf2 dead)
    const unsigned short* Wg = Wbf + 49152;
    float* Of = Obnc + wv*1600;     // [32ch][49tok] stride 50
    s16x8 bfr[2][4]; float ob[2];
    #pragma unroll
    for (int ntl = 0; ntl < 2; ++ntl) {
      int col = wv*32 + ntl*16 + lr;
      ob[ntl] = bo[col];
      #pragma unroll
      for (int ks = 0; ks < 4; ++ks)
        bfr[ntl][ks] = *(const s16x8*)(Wg + col*CC + ks*32 + lg*8);
    }
    #pragma unroll
    for (int mt = 0; mt < 4; ++mt) {
      int ar = mt*16 + lr;
      s16x8 af[4];
      #pragma unroll
      for (int ks = 0; ks < 4; ++ks)
        af[ks] = *(const s16x8*)(Buf0 + ar*CC + swz8(ar, ks*32 + lg*8));
      #pragma unroll
      for (int ntl = 0; ntl < 2; ++ntl) {
        f32x4 a = {0.f,0.f,0.f,0.f};
        #pragma unroll
        for (int ks = 0; ks < 4; ++ks)
          a = __builtin_amdgcn_mfma_f32_16x16x32_bf16(af[ks], bfr[ntl][ks], a, 0,0,0);
        #pragma unroll
        for (int r = 0; r < 4; ++r) {
          int row = mt*16 + lg*4 + r;
          if (row < NTOK)
            Of[(ntl*16 + lr)*50 + row] = a[r] + ob[ntl];
        }
      }
    }
    // wave-local dump: lane=linear element -> ~10 lines/inst instead of 64
    int chb = bimg*CC + wv*32;
    #pragma unroll
    for (int it = 0; it < 25; ++it) {
      int e = it*64 + l;
      if (e < 32*NTOK) {
        int ch = e / NTOK, tok = e - ch*NTOK;
        int si = tok / 7, sj = tok - si*7;
        out_x[(size_t)(chb + ch)*HW2 + (size_t)(r0+si)*HWW + (c0+sj)] = Of[ch*50 + tok];
      }
    }
  }
}

extern "C" void kernel_launch(void* const* d_in, const int* in_sizes, int n_in,
                              void* d_out, int out_size, void* d_ws, size_t ws_size,
                              hipStream_t stream) {
  (void)in_sizes; (void)n_in; (void)out_size; (void)ws_size;
  const float* query = (const float*)d_in[0];
  const float* key   = (const float*)d_in[1];
  const float* value = (const float*)d_in[2];
  const float* Wq = (const float*)d_in[3];
  const float* bq = (const float*)d_in[4];
  const float* Wk = (const float*)d_in[5];
  const float* bk = (const float*)d_in[6];
  const float* Wv = (const float*)d_in[7];
  const float* bv = (const float*)d_in[8];
  const float* Wo = (const float*)d_in[9];
  const float* bo = (const float*)d_in[10];
  const float* rpb = (const float*)d_in[11];

  unsigned short* Wbf = (unsigned short*)d_ws;                  // 128 KB bf16 weights
  float* Biasg = (float*)((char*)d_ws + 131072);                // 38.4 KB bias table
  float* out_x   = (float*)d_out;                               // [64][128][56][56] fp32
  float* out_ctx = out_x + (size_t)64*CC*HW2;                   // [4096][4][49][49] fp32

  prep_kernel<<<294, 256, 0, stream>>>(Wq, Wk, Wv, Wo, rpb, Wbf, Biasg);
  winattn_kernel<<<4096, 256, 0, stream>>>(query, key, value, Wbf, Biasg,
                                           bq, bk, bv, bo, out_x, out_ctx);
}